// Round 6
// baseline (1224.845 us; speedup 1.0000x reference)
//
#include <hip/hip_runtime.h>
#include <cstddef>

#define BB 2
#define LL 1024
#define DM 768
#define DI 1536
#define NST 16
#define DTR 48
#define DINT 1536
#define NLAYER 2
#define ML (BB*LL)      /* 2048 rows per direction */
#define NCH 32
#define CLEN (LL/NCH)   /* 32 */

typedef __attribute__((ext_vector_type(8))) short s16x8;
typedef __attribute__((ext_vector_type(4))) float f32x4;

typedef __attribute__((address_space(1))) void* gas_t;   /* non-const: builtin proto is v*1 */
typedef __attribute__((address_space(3))) void* las_t;

static __device__ __forceinline__ float sigm(float x){ return 1.f/(1.f+__expf(-x)); }
static __device__ __forceinline__ float silu_(float x){ return x*sigm(x); }
static __device__ __forceinline__ float softplus_(float x){ return fmaxf(x,0.f)+log1pf(__expf(-fabsf(x))); }
static __device__ __forceinline__ unsigned short f2b(float x){
  unsigned int u = __float_as_uint(x);
  unsigned int r = (u + 0x7fffu + ((u>>16)&1u)) >> 16;
  return (unsigned short)r;
}
static __device__ __forceinline__ float b2f(unsigned short v){
  return __uint_as_float(((unsigned int)v) << 16);
}
// Journal: R6: 128x128 grid-starved (416 blk) 1286us; R7: 128x64 1228us.
// R8/R9: gload_lds staging NEUTRAL. R10: dbuf+syncthreads NEUTRAL.
// R11: dbuf+counted-vmcnt NEUTRAL. R12: XCD swizzle: FETCH 62->28MB (2.2x)
//     but dur IDENTICAL (101us) -> time invariant to data source AND issue
//     timing. Invariant left: per-K-step structure (2 barriers + 3 gload_lds
//     wave-ops/thread; ~1560cyc per block-step; ~7.7 B/cyc/CU staging).
// R13: A/B test per-step vs per-byte: BK=64 (24 steps, 2x bytes/step, same
//     total bytes). dbuf LDS 48KB (3 blk/CU). Per-step-bound -> ~2x GEMMs;
//     per-byte-bound -> neutral -> pivot to AI-raising (128x128 / fp8).

__global__ void k_embed(const int* __restrict__ ids, const float* __restrict__ emb,
                        float* __restrict__ out){
  int idx = blockIdx.x*256 + threadIdx.x;
  if (idx >= ML*DM) return;
  int c = idx % DM; int bl = idx / DM;
  out[idx] = emb[(size_t)ids[bl]*DM + c];
}

struct Seg8 { const float* src[8]; unsigned short* dst[8]; int cum[9]; };
__global__ void k_f2bseg(Seg8 p){
  int idx = blockIdx.x*256 + threadIdx.x;
  if (idx >= p.cum[8]) return;
  int s = 0;
  #pragma unroll
  for (int i = 1; i < 8; i++) s += (idx >= p.cum[i]);
  int local = idx - p.cum[s];
  p.dst[s][local] = f2b(p.src[s][local]);
}

// wbig for ONE layer: rows<1536 = dt_w @ x_proj[:48]; rows 1536..1663 = x_proj[48:80]/pad
__global__ void k_wbig(const float* __restrict__ dw, const float* __restrict__ xp,
                       unsigned short* __restrict__ wb){
  int idx = blockIdx.x*256 + threadIdx.x;   // over 1664*DI
  if (idx >= 1664*DI) return;
  int j = idx % DI, i = idx / DI;
  unsigned short v;
  if (i < DI){
    float s = 0.f;
    #pragma unroll
    for (int k = 0; k < DTR; k++) s += dw[i*DTR + k] * xp[(size_t)k*DI + j];
    v = f2b(s);
  } else {
    int r = i - DI;
    v = (r < 32) ? f2b(xp[(size_t)(DTR + r)*DI + j]) : (unsigned short)0;
  }
  wb[idx] = v;
}

__global__ __launch_bounds__(256) void k_ln(const float* __restrict__ x,
    const float* __restrict__ add, const float* __restrict__ w, const float* __restrict__ bi,
    float* __restrict__ sumout, float* __restrict__ fout, unsigned short* __restrict__ bout,
    int rows){
  int wv = threadIdx.x >> 6, lane = threadIdx.x & 63;
  int row = blockIdx.x*4 + wv;
  if (row >= rows) return;
  const float* xr = x + (size_t)row*DM;
  float v[12]; float s = 0.f, sq = 0.f;
  #pragma unroll
  for (int i = 0; i < 12; i++){
    int c = lane + 64*i;
    float t = xr[c];
    if (add) t += add[(size_t)row*DM + c];
    if (sumout) sumout[(size_t)row*DM + c] = t;
    v[i] = t; s += t; sq += t*t;
  }
  #pragma unroll
  for (int o = 32; o; o >>= 1){ s += __shfl_xor(s, o, 64); sq += __shfl_xor(sq, o, 64); }
  float mean = s*(1.f/DM);
  float var  = sq*(1.f/DM) - mean*mean;
  float rstd = rsqrtf(var + 1e-5f);
  #pragma unroll
  for (int i = 0; i < 12; i++){
    int c = lane + 64*i;
    float o = (v[i]-mean)*rstd*w[c] + bi[c];
    if (fout) fout[(size_t)row*DM + c] = o;
    if (bout) bout[(size_t)row*DM + c] = f2b(o);
  }
}

__global__ __launch_bounds__(256) void k_lnfin(const float* __restrict__ mlpo,
    const float* __restrict__ resd, const float* __restrict__ w, const float* __restrict__ bi,
    float* __restrict__ h, float* __restrict__ res){
  int wv = threadIdx.x >> 6, lane = threadIdx.x & 63;
  int row = blockIdx.x*4 + wv;
  if (row >= ML) return;
  const float* x0 = mlpo + (size_t)row*DM;
  const float* x1 = mlpo + (size_t)(ML + row)*DM;
  float v0[12], v1[12]; float s0=0,q0=0,s1=0,q1=0;
  #pragma unroll
  for (int i = 0; i < 12; i++){
    int c = lane + 64*i;
    float a = x0[c], b = x1[c];
    v0[i]=a; v1[i]=b; s0+=a; q0+=a*a; s1+=b; q1+=b*b;
  }
  #pragma unroll
  for (int o = 32; o; o >>= 1){
    s0 += __shfl_xor(s0, o, 64); q0 += __shfl_xor(q0, o, 64);
    s1 += __shfl_xor(s1, o, 64); q1 += __shfl_xor(q1, o, 64);
  }
  float m0 = s0*(1.f/DM), m1 = s1*(1.f/DM);
  float r0 = rsqrtf(q0*(1.f/DM) - m0*m0 + 1e-5f);
  float r1 = rsqrtf(q1*(1.f/DM) - m1*m1 + 1e-5f);
  #pragma unroll
  for (int i = 0; i < 12; i++){
    int c = lane + 64*i;
    float o = ((v0[i]-m0)*r0 + (v1[i]-m1)*r1)*w[c] + 2.f*bi[c];
    h[(size_t)row*DM + c] = o;
    res[(size_t)row*DM + c] = resd[(size_t)row*DM + c] + resd[(size_t)(ML+row)*DM + c];
  }
}

// Bijective XCD-chunk remap (m204), m-major decompose (kept: halved FETCH_SIZE).
static __device__ __forceinline__ void tile_mn(int &mT, int &nT){
  int nx = gridDim.x;
  int orig = blockIdx.y * nx + blockIdx.x;
  int nwg = nx * gridDim.y;
  int q = nwg >> 3, r = nwg & 7;
  int xcd = orig & 7, j = orig >> 3;
  int wg = (xcd < r ? xcd*(q+1) : r*(q+1) + (xcd-r)*q) + j;
  mT = wg / nx; nT = wg - mT*nx;
}

// ---- MFMA GEMM core: 128(M) x 64(N) tile, BK=64, dbuf + counted vmcnt ----
// LDS per buf: A 16KB (two 8KB BK=32 subtiles), B 8KB (two 4KB subtiles).
// 6 gload_lds wave-ops/thread/step; wait vmcnt(6) before consuming a buffer.
static __device__ __forceinline__ void mgemm_core(
    const unsigned short* __restrict__ A, const unsigned short* __restrict__ W, int K,
    int m0, int n0,
    unsigned short* As, unsigned short* Bs, f32x4 (&acc)[4][2]){
  int t = threadIdx.x;
  int lane = t & 63, w = t >> 6;
  int wm = w & 1, wn = w >> 1;

  const unsigned short* gA[4]; unsigned short* lA[4];
  #pragma unroll
  for (int si = 0; si < 4; si++){
    int s = t + si*256;           // 0..1023 over A tile (128 rows x 64 k)
    int kk = s >> 9, s2 = s & 511;
    int row = ((s2>>6)<<4) + (s2 & 15);
    int ko  = (((s2>>4) & 3) << 3) + kk*32;
    gA[si] = A + (size_t)(m0+row)*K + ko;
    lA[si] = As + (size_t)s*8;    // linear: s*16B
  }
  const unsigned short* gB[2]; unsigned short* lB[2];
  #pragma unroll
  for (int si = 0; si < 2; si++){
    int s = t + si*256;           // 0..511 over B tile (64 rows x 64 k)
    int kk = s >> 8, s2 = s & 255;
    int row = ((s2>>6)<<4) + (s2 & 15);
    int ko  = (((s2>>4) & 3) << 3) + kk*32;
    gB[si] = W + (size_t)(n0+row)*K + ko;
    lB[si] = Bs + (size_t)s*8;
  }

  // prologue: stage step 0 into buf 0
  #pragma unroll
  for (int si = 0; si < 4; si++)
    __builtin_amdgcn_global_load_lds((gas_t)gA[si], (las_t)lA[si], 16, 0, 0);
  #pragma unroll
  for (int si = 0; si < 2; si++)
    __builtin_amdgcn_global_load_lds((gas_t)gB[si], (las_t)lB[si], 16, 0, 0);

  int NI = K >> 6;
  int cur = 0;
  for (int it = 0; it < NI; ++it){
    if (it + 1 < NI){
      int kn = (it+1) << 6, nb = cur ^ 1;
      #pragma unroll
      for (int si = 0; si < 4; si++)
        __builtin_amdgcn_global_load_lds((gas_t)(gA[si] + kn), (las_t)(lA[si] + nb*8192), 16, 0, 0);
      #pragma unroll
      for (int si = 0; si < 2; si++)
        __builtin_amdgcn_global_load_lds((gas_t)(gB[si] + kn), (las_t)(lB[si] + nb*4096), 16, 0, 0);
      asm volatile("s_waitcnt vmcnt(6)" ::: "memory");   // own 6 for 'cur' landed
    } else {
      asm volatile("s_waitcnt vmcnt(0)" ::: "memory");
    }
    __builtin_amdgcn_s_barrier();
    __builtin_amdgcn_sched_barrier(0);
    const unsigned short* Ab = As + cur*8192;
    const unsigned short* Bb = Bs + cur*4096;
    #pragma unroll
    for (int kk = 0; kk < 2; kk++){
      s16x8 af[4], bf[2];
      #pragma unroll
      for (int i = 0; i < 4; i++) af[i] = *(const s16x8*)&Ab[kk*4096 + ((wm*4+i)*64 + lane)*8];
      #pragma unroll
      for (int j = 0; j < 2; j++) bf[j] = *(const s16x8*)&Bb[kk*2048 + ((wn*2+j)*64 + lane)*8];
      #pragma unroll
      for (int i = 0; i < 4; i++)
        #pragma unroll
        for (int j = 0; j < 2; j++)
          acc[i][j] = __builtin_amdgcn_mfma_f32_16x16x32_bf16(af[i], bf[j], acc[i][j], 0, 0, 0);
    }
    __builtin_amdgcn_s_barrier();   // all waves done reading 'cur'
    __builtin_amdgcn_sched_barrier(0);
    cur ^= 1;
  }
}

__global__ __launch_bounds__(256) void k_mg0(const unsigned short* __restrict__ A,
    const unsigned short* __restrict__ W, const float* __restrict__ addsrc,
    float* __restrict__ Cf, int N, int K){
  __shared__ __align__(16) unsigned short As[16384], Bs[8192];
  int mT, nT; tile_mn(mT, nT);
  int m0 = mT*128, n0 = nT*64;
  f32x4 acc[4][2] = {};
  mgemm_core(A, W, K, m0, n0, As, Bs, acc);
  int t = threadIdx.x, lane = t & 63, w = t >> 6;
  int wm = w & 1, wn = w >> 1;
  int cl = lane & 15, qd = lane >> 4;
  #pragma unroll
  for (int i = 0; i < 4; i++){
    int mbase = m0 + (wm*4+i)*16 + qd*4;
    #pragma unroll
    for (int j = 0; j < 2; j++){
      int n = n0 + (wn*2+j)*16 + cl;
      #pragma unroll
      for (int r = 0; r < 4; r++){
        int m = mbase + r;
        float v = acc[i][j][r];
        if (addsrc) v += addsrc[(size_t)(m & (ML-1))*N + n];
        Cf[(size_t)m*N + n] = v;
      }
    }
  }
}

__global__ __launch_bounds__(256) void k_mg1(const unsigned short* __restrict__ A,
    const unsigned short* __restrict__ W, const float* __restrict__ dtb,
    unsigned short* __restrict__ dlb, float* __restrict__ bcout, int K){
  __shared__ __align__(16) unsigned short As[16384], Bs[8192];
  int mT, nT; tile_mn(mT, nT);
  int m0 = mT*128, n0 = nT*64;
  f32x4 acc[4][2] = {};
  mgemm_core(A, W, K, m0, n0, As, Bs, acc);
  int t = threadIdx.x, lane = t & 63, w = t >> 6;
  int wm = w & 1, wn = w >> 1;
  int cl = lane & 15, qd = lane >> 4;
  #pragma unroll
  for (int i = 0; i < 4; i++){
    int mbase = m0 + (wm*4+i)*16 + qd*4;
    #pragma unroll
    for (int j = 0; j < 2; j++){
      int n = n0 + (wn*2+j)*16 + cl;
      #pragma unroll
      for (int r = 0; r < 4; r++){
        int m = mbase + r;
        float v = acc[i][j][r];
        if (n < DI) dlb[(size_t)m*DI + n] = f2b(softplus_(v + dtb[n]));
        else if (n < DI + 32) bcout[(size_t)m*32 + (n - DI)] = v;
      }
    }
  }
}

__global__ __launch_bounds__(256) void k_mg2(const unsigned short* __restrict__ A,
    const unsigned short* __restrict__ W, unsigned short* __restrict__ Cb, int N, int K){
  __shared__ __align__(16) unsigned short As[16384], Bs[8192];
  int mT, nT; tile_mn(mT, nT);
  int m0 = mT*128, n0 = nT*64;
  f32x4 acc[4][2] = {};
  mgemm_core(A, W, K, m0, n0, As, Bs, acc);
  int t = threadIdx.x, lane = t & 63, w = t >> 6;
  int wm = w & 1, wn = w >> 1;
  int cl = lane & 15, qd = lane >> 4;
  #pragma unroll
  for (int i = 0; i < 4; i++){
    int mbase = m0 + (wm*4+i)*16 + qd*4;
    #pragma unroll
    for (int j = 0; j < 2; j++){
      int n = n0 + (wn*2+j)*16 + cl;
      #pragma unroll
      for (int r = 0; r < 4; r++){
        int m = mbase + r;
        Cb[(size_t)m*N + n] = f2b(acc[i][j][r]);
      }
    }
  }
}

__global__ void k_conv(const unsigned short* __restrict__ xzb, const float* __restrict__ w,
                       const float* __restrict__ bi, unsigned short* __restrict__ xcb){
  int idx = blockIdx.x*256 + threadIdx.x;   // over 2*ML*DI
  if (idx >= 2*ML*DI) return;
  int d = idx % DI; int r = idx / DI;
  int bl = r % ML; int dir = r / ML;
  int t = bl % LL; int b = bl / LL;
  float acc = bi[d];
  #pragma unroll
  for (int k = 0; k < 4; k++){
    int tp = dir ? (t + 3 - k) : (t - 3 + k);
    if (tp >= 0 && tp < LL)
      acc += w[d*4 + k] * b2f(xzb[((size_t)(b*LL + tp))*(2*DI) + d]);
  }
  xcb[idx] = f2b(silu_(acc));
}

__global__ __launch_bounds__(256) void k_scan1(
    const unsigned short* __restrict__ dlb, const unsigned short* __restrict__ xcb,
    const float* __restrict__ bc, const float* __restrict__ A_log,
    float* __restrict__ sA, float* __restrict__ sH){
  __shared__ float Bsh[CLEN*16];
  int blk = blockIdx.x;
  int dgrp = blk % (DI/256); int rest = blk / (DI/256);
  int ch = rest % NCH; rest /= NCH;
  int b = rest & 1; int dir = rest >> 1;
  int d = dgrp*256 + threadIdx.x;
  int t0 = dir ? (LL-1 - ch*CLEN) : ch*CLEN;
  long step = dir ? -1 : 1;
  long row0 = (long)dir*ML + b*LL + t0;
  #pragma unroll
  for (int rep = 0; rep < CLEN*16/256; rep++){
    int e = threadIdx.x + rep*256;
    int s = e >> 4, n = e & 15;
    Bsh[e] = bc[(size_t)(row0 + s*step)*32 + n];
  }
  __syncthreads();
  float ea[16];
  #pragma unroll
  for (int n = 0; n < 16; n++) ea[n] = -__expf(A_log[d*16 + n]) * 1.44269504f;
  float h[16], P[16];
  #pragma unroll
  for (int n = 0; n < 16; n++){ h[n] = 0.f; P[n] = 1.f; }
  long row = row0;
  for (int s = 0; s < CLEN; s++){
    float de = b2f(dlb[(size_t)row*DI + d]);
    float u  = b2f(xcb[(size_t)row*DI + d]);
    float duu = de*u;
    float Ba[16];
    const f32x4* Bv = (const f32x4*)&Bsh[s*16];
    *(f32x4*)&Ba[0] = Bv[0]; *(f32x4*)&Ba[4] = Bv[1];
    *(f32x4*)&Ba[8] = Bv[2]; *(f32x4*)&Ba[12] = Bv[3];
    #pragma unroll
    for (int n = 0; n < 16; n++){
      float dA = exp2f(de*ea[n]);
      h[n] = dA*h[n] + duu*Ba[n];
      P[n] *= dA;
    }
    row += step;
  }
  size_t sbase = ((((size_t)dir*BB + b)*NCH + ch)*DI + d)*16;
  #pragma unroll
  for (int n = 0; n < 16; n++){ sA[sbase+n] = P[n]; sH[sbase+n] = h[n]; }
}

__global__ __launch_bounds__(256) void k_prefix(
    float* __restrict__ sA, const float* __restrict__ sH){
  int gid = blockIdx.x*256 + threadIdx.x;  // over 2*BB*DI*16
  int dn = gid % (DI*16);
  int db_ = gid / (DI*16);
  float h = 0.f;
  size_t base = (size_t)db_*NCH*DI*16 + dn;
  for (int ch = 0; ch < NCH; ch++){
    size_t idx = base + (size_t)ch*DI*16;
    float a = sA[idx], hh = sH[idx];
    sA[idx] = h;
    h = hh + a*h;
  }
}

__global__ __launch_bounds__(256) void k_scan2(
    const unsigned short* __restrict__ dlb, const unsigned short* __restrict__ xcb,
    const float* __restrict__ bc, const unsigned short* __restrict__ xzb,
    const float* __restrict__ A_log, const float* __restrict__ Dp,
    const float* __restrict__ h0, unsigned short* __restrict__ y){
  __shared__ float BCs[CLEN*32];
  int blk = blockIdx.x;
  int dgrp = blk % (DI/256); int rest = blk / (DI/256);
  int ch = rest % NCH; rest /= NCH;
  int b = rest & 1; int dir = rest >> 1;
  int d = dgrp*256 + threadIdx.x;
  int t0 = dir ? (LL-1 - ch*CLEN) : ch*CLEN;
  long step = dir ? -1 : 1;
  long row0 = (long)dir*ML + b*LL + t0;
  #pragma unroll
  for (int rep = 0; rep < CLEN*32/256; rep++){
    int e = threadIdx.x + rep*256;
    int s = e >> 5, n = e & 31;
    BCs[e] = bc[(size_t)(row0 + s*step)*32 + n];
  }
  __syncthreads();
  float ea[16];
  #pragma unroll
  for (int n = 0; n < 16; n++) ea[n] = -__expf(A_log[d*16 + n]) * 1.44269504f;
  float dD = Dp[d];
  float h[16];
  size_t hbase = ((((size_t)dir*BB + b)*NCH + ch)*DI + d)*16;
  #pragma unroll
  for (int n = 0; n < 16; n++) h[n] = h0[hbase + n];
  long row = row0;
  long zoff = (long)dir*ML;
  for (int s = 0; s < CLEN; s++){
    float de = b2f(dlb[(size_t)row*DI + d]);
    float u  = b2f(xcb[(size_t)row*DI + d]);
    float z  = b2f(xzb[(size_t)(row - zoff)*(2*DI) + DI + d]);
    float duu = de*u;
    float Ba[16], Ca[16];
    const f32x4* Bv = (const f32x4*)&BCs[s*32];
    *(f32x4*)&Ba[0] = Bv[0]; *(f32x4*)&Ba[4] = Bv[1];
    *(f32x4*)&Ba[8] = Bv[2]; *(f32x4*)&Ba[12] = Bv[3];
    *(f32x4*)&Ca[0] = Bv[4]; *(f32x4*)&Ca[4] = Bv[5];
    *(f32x4*)&Ca[8] = Bv[6]; *(f32x4*)&Ca[12] = Bv[7];
    float p0 = 0.f, p1 = 0.f, p2 = 0.f, p3 = 0.f;
    #pragma unroll
    for (int n = 0; n < 16; n += 4){
      float dA0 = exp2f(de*ea[n]),   dA1 = exp2f(de*ea[n+1]);
      float dA2 = exp2f(de*ea[n+2]), dA3 = exp2f(de*ea[n+3]);
      h[n]   = dA0*h[n]   + duu*Ba[n];
      h[n+1] = dA1*h[n+1] + duu*Ba[n+1];
      h[n+2] = dA2*h[n+2] + duu*Ba[n+2];
      h[n+3] = dA3*h[n+3] + duu*Ba[n+3];
      p0 = fmaf(h[n],   Ca[n],   p0);
      p1 = fmaf(h[n+1], Ca[n+1], p1);
      p2 = fmaf(h[n+2], Ca[n+2], p2);
      p3 = fmaf(h[n+3], Ca[n+3], p3);
    }
    float p = (p0+p1) + (p2+p3);
    y[(size_t)row*DI + d] = f2b((p + u*dD) * silu_(z));
    row += step;
  }
}

__global__ void k_gate(const unsigned short* __restrict__ fc1o, unsigned short* __restrict__ g){
  int idx = blockIdx.x*256 + threadIdx.x;   // over 2*ML*DINT
  if (idx >= 2*ML*DINT) return;
  int i = idx % DINT; int bl = idx / DINT;
  float aa = b2f(fc1o[(size_t)bl*2*DINT + i]);
  float gt = b2f(fc1o[(size_t)bl*2*DINT + DINT + i]);
  g[idx] = f2b(aa * silu_(gt));
}

__global__ void k_mean(const float* __restrict__ x, float* __restrict__ out){
  int d = blockIdx.x*256 + threadIdx.x;
  int b = blockIdx.y;
  if (d >= DM) return;
  float s = 0.f;
  for (int t = 0; t < LL; t++) s += x[((size_t)(b*LL + t))*DM + d];
  out[b*DM + d] = s*(1.f/LL);
}

extern "C" void kernel_launch(void* const* d_in, const int* in_sizes, int n_in,
                              void* d_out, int out_size, void* d_ws, size_t ws_size,
                              hipStream_t stream){
  const int*   ids     = (const int*)d_in[0];
  const float* embed   = (const float*)d_in[1];
  const float* norm_w  = (const float*)d_in[2];
  const float* norm_b  = (const float*)d_in[3];
  const float* in_proj = (const float*)d_in[4];
  const float* conv_w  = (const float*)d_in[5];
  const float* conv_b  = (const float*)d_in[6];
  const float* x_proj  = (const float*)d_in[7];
  const float* dt_w    = (const float*)d_in[8];
  const float* dt_b    = (const float*)d_in[9];
  const float* A_log   = (const float*)d_in[10];
  const float* Dp      = (const float*)d_in[11];
  const float* out_pj  = (const float*)d_in[12];
  const float* norm2_w = (const float*)d_in[13];
  const float* norm2_b = (const float*)d_in[14];
  const float* fc1     = (const float*)d_in[15];
  const float* fc2     = (const float*)d_in[16];
  const float* normf_w = (const float*)d_in[17];
  const float* normf_b = (const float*)d_in[18];
  float* out = (float*)d_out;

  const size_t BLD   = (size_t)ML*DM;
  const size_t BLDI  = (size_t)ML*DI;
  const size_t SUMN  = (size_t)2*BB*NCH*DI*16;

  float* f = (float*)d_ws; size_t off = 0;
  float* h     = f+off; off += BLD;
  float* res   = f+off; off += BLD;
  float* rc    = f+off; off += BLD;
  float* resd  = f+off; off += 2*BLD;
  float* bc    = f+off; off += (size_t)2*ML*32;
  float* sA    = f+off; off += SUMN;    // h0 overwrites in place
  float* sH    = f+off; off += SUMN;    // gb aliases after prefix
  unsigned short* gb = (unsigned short*)sH;
  unsigned short* u16 = (unsigned short*)(f + off); size_t uo = 0;
  unsigned short* xlnb = u16+uo; uo += BLD;
  unsigned short* x2b  = u16+uo; uo += 2*BLD;
  unsigned short* xzb  = u16+uo; uo += 2*BLDI;
  unsigned short* xcb  = u16+uo; uo += 2*BLDI;
  unsigned short* dlb  = u16+uo; uo += 2*BLDI;
  unsigned short* wts  = u16+uo;
  const size_t W_IP = (size_t)2*DI*DM, W_OP = (size_t)DM*DI, W_F1 = (size_t)2*DINT*DM,
               W_F2 = (size_t)DM*DINT, W_BG = (size_t)1664*DI;
  const size_t WLAY = W_IP + W_OP + W_F1 + W_F2 + W_BG;
  unsigned short* yb   = xcb;
  unsigned short* fc1o = xcb;            // spans xcb+dlb
  float*          mlpo = (float*)xcb;    // after fc1o dead
  (void)ws_size; (void)in_sizes; (void)n_in; (void)out_size;

  dim3 blk(256);
  auto cdiv = [](int a, int b){ return (a + b - 1)/b; };
  const int scan_blocks = 2*2*NCH*(DI/256);

  // weight prep (both layers, 3 launches, no activation deps)
  Seg8 sg; int cum = 0;
  for (int l = 0; l < 2; l++){
    unsigned short* wl = wts + (size_t)l*WLAY;
    sg.src[l*4+0] = in_proj + (size_t)l*W_IP; sg.dst[l*4+0] = wl;
    sg.src[l*4+1] = out_pj  + (size_t)l*W_OP; sg.dst[l*4+1] = wl + W_IP;
    sg.src[l*4+2] = fc1     + (size_t)l*W_F1; sg.dst[l*4+2] = wl + W_IP + W_OP;
    sg.src[l*4+3] = fc2     + (size_t)l*W_F2; sg.dst[l*4+3] = wl + W_IP + W_OP + W_F1;
  }
  { int sz[8] = {(int)W_IP,(int)W_OP,(int)W_F1,(int)W_F2,(int)W_IP,(int)W_OP,(int)W_F1,(int)W_F2};
    sg.cum[0]=0; for (int i = 0; i < 8; i++){ cum += sz[i]; sg.cum[i+1] = cum; } }
  k_f2bseg<<<cdiv(cum,256), blk, 0, stream>>>(sg);
  for (int l = 0; l < 2; l++)
    k_wbig<<<cdiv(1664*DI,256), blk, 0, stream>>>(dt_w + (size_t)l*DI*DTR,
        x_proj + (size_t)l*(DTR+2*NST)*DI, wts + (size_t)l*WLAY + W_IP + W_OP + W_F1 + W_F2);

  k_embed<<<cdiv(ML*DM,256), blk, 0, stream>>>(ids, embed, h);

  for (int l = 0; l < NLAYER; l++){
    unsigned short* wl   = wts + (size_t)l*WLAY;
    unsigned short* wib  = wl;
    unsigned short* wob  = wl + W_IP;
    unsigned short* wf1b = wl + W_IP + W_OP;
    unsigned short* wf2b = wl + W_IP + W_OP + W_F1;
    unsigned short* wbig = wl + W_IP + W_OP + W_F1 + W_F2;
    const float* nw  = norm_w  + l*DM;
    const float* nb  = norm_b  + l*DM;
    const float* cw  = conv_w  + (size_t)l*DI*4;
    const float* cb  = conv_b  + (size_t)l*DI;
    const float* db  = dt_b    + (size_t)l*DI;
    const float* al  = A_log   + (size_t)l*DI*NST;
    const float* dpl = Dp      + (size_t)l*DI;
    const float* n2w = norm2_w + l*DM;
    const float* n2b = norm2_b + l*DM;

    k_ln<<<ML/4, blk, 0, stream>>>(h, (l==0)?nullptr:res, nw, nb, rc, nullptr, xlnb, ML);
    k_mg2<<<dim3(2*DI/64, ML/128), blk, 0, stream>>>(xlnb, wib, xzb, 2*DI, DM);
    k_conv<<<cdiv(2*ML*DI,256), blk, 0, stream>>>(xzb, cw, cb, xcb);
    k_mg1<<<dim3(1664/64, 2*ML/128), blk, 0, stream>>>(xcb, wbig, db, dlb, bc, DI);
    k_scan1<<<scan_blocks, blk, 0, stream>>>(dlb, xcb, bc, al, sA, sH);
    k_prefix<<<(2*BB*DI*16)/256, blk, 0, stream>>>(sA, sH);
    k_scan2<<<scan_blocks, blk, 0, stream>>>(dlb, xcb, bc, xzb, al, dpl, sA, yb);
    k_mg0<<<dim3(DM/64, 2*ML/128), blk, 0, stream>>>(yb, wob, rc, resd, DM, DI);
    k_ln<<<2*ML/4, blk, 0, stream>>>(resd, nullptr, n2w, n2b, nullptr, nullptr, x2b, 2*ML);
    k_mg2<<<dim3(2*DINT/64, 2*ML/128), blk, 0, stream>>>(x2b, wf1b, fc1o, 2*DINT, DM);
    k_gate<<<cdiv(2*ML*DINT,256), blk, 0, stream>>>(fc1o, gb);
    k_mg0<<<dim3(DM/64, 2*ML/128), blk, 0, stream>>>(gb, wf2b, nullptr, mlpo, DM, DINT);
    k_lnfin<<<ML/4, blk, 0, stream>>>(mlpo, resd, normf_w, normf_b, h, res);
  }

  k_ln<<<ML/4, blk, 0, stream>>>(h, res, normf_w, normf_b, nullptr, rc, nullptr, ML);
  k_mean<<<dim3(3, BB), blk, 0, stream>>>(rc, out);
}

// Round 8
// 1096.704 us; speedup vs baseline: 1.1168x; 1.1168x over previous
//
#include <hip/hip_runtime.h>
#include <cstddef>

#define BB 2
#define LL 1024
#define DM 768
#define DI 1536
#define NST 16
#define DTR 48
#define DINT 1536
#define NLAYER 2
#define ML (BB*LL)      /* 2048 rows per direction */
#define NCH 32
#define CLEN (LL/NCH)   /* 32 */

typedef __attribute__((ext_vector_type(8))) short s16x8;
typedef __attribute__((ext_vector_type(4))) float f32x4;

typedef __attribute__((address_space(1))) void* gas_t;   /* non-const: builtin proto is v*1 */
typedef __attribute__((address_space(3))) void* las_t;

static __device__ __forceinline__ float sigm(float x){ return 1.f/(1.f+__expf(-x)); }
static __device__ __forceinline__ float silu_(float x){ return x*sigm(x); }
static __device__ __forceinline__ float softplus_(float x){ return fmaxf(x,0.f)+log1pf(__expf(-fabsf(x))); }
static __device__ __forceinline__ unsigned short f2b(float x){
  unsigned int u = __float_as_uint(x);
  unsigned int r = (u + 0x7fffu + ((u>>16)&1u)) >> 16;
  return (unsigned short)r;
}
static __device__ __forceinline__ float b2f(unsigned short v){
  return __uint_as_float(((unsigned int)v) << 16);
}
// Journal: R8-R13 all NEUTRAL on k_mg1 (100-104us): staging method, dbuf,
//   counted vmcnt, XCD swizzle (FETCH 62->28MB!), BK=64. Model fitting ALL:
//   per-byte staging limit ~9-10 B/cyc/CU; GEMM time = staged bytes / 4.9TB/s.
// R14: 128x128 tiles for mg1/mg2 (staged bytes x0.67) -> NaN: dbuf WRITE
//   offsets were in byte-units on short* pointers (nb*8192 / nb*BBUF-bytes),
//   buffer-1 stage landed past As[] into Bs[]. Reads were correct.
// R15: same design, strides fixed in SHORTS: ABUF=4096, BBUFS=TN*32 used on
//   BOTH write and read side. Prediction: mg1 101->~67us, total ~1030-1070.

__global__ void k_embed(const int* __restrict__ ids, const float* __restrict__ emb,
                        float* __restrict__ out){
  int idx = blockIdx.x*256 + threadIdx.x;
  if (idx >= ML*DM) return;
  int c = idx % DM; int bl = idx / DM;
  out[idx] = emb[(size_t)ids[bl]*DM + c];
}

struct Seg8 { const float* src[8]; unsigned short* dst[8]; int cum[9]; };
__global__ void k_f2bseg(Seg8 p){
  int idx = blockIdx.x*256 + threadIdx.x;
  if (idx >= p.cum[8]) return;
  int s = 0;
  #pragma unroll
  for (int i = 1; i < 8; i++) s += (idx >= p.cum[i]);
  int local = idx - p.cum[s];
  p.dst[s][local] = f2b(p.src[s][local]);
}

// wbig for ONE layer: rows<1536 = dt_w @ x_proj[:48]; rows 1536..1663 = x_proj[48:80]/pad
__global__ void k_wbig(const float* __restrict__ dw, const float* __restrict__ xp,
                       unsigned short* __restrict__ wb){
  int idx = blockIdx.x*256 + threadIdx.x;   // over 1664*DI
  if (idx >= 1664*DI) return;
  int j = idx % DI, i = idx / DI;
  unsigned short v;
  if (i < DI){
    float s = 0.f;
    #pragma unroll
    for (int k = 0; k < DTR; k++) s += dw[i*DTR + k] * xp[(size_t)k*DI + j];
    v = f2b(s);
  } else {
    int r = i - DI;
    v = (r < 32) ? f2b(xp[(size_t)(DTR + r)*DI + j]) : (unsigned short)0;
  }
  wb[idx] = v;
}

__global__ __launch_bounds__(256) void k_ln(const float* __restrict__ x,
    const float* __restrict__ add, const float* __restrict__ w, const float* __restrict__ bi,
    float* __restrict__ sumout, float* __restrict__ fout, unsigned short* __restrict__ bout,
    int rows){
  int wv = threadIdx.x >> 6, lane = threadIdx.x & 63;
  int row = blockIdx.x*4 + wv;
  if (row >= rows) return;
  const float* xr = x + (size_t)row*DM;
  float v[12]; float s = 0.f, sq = 0.f;
  #pragma unroll
  for (int i = 0; i < 12; i++){
    int c = lane + 64*i;
    float t = xr[c];
    if (add) t += add[(size_t)row*DM + c];
    if (sumout) sumout[(size_t)row*DM + c] = t;
    v[i] = t; s += t; sq += t*t;
  }
  #pragma unroll
  for (int o = 32; o; o >>= 1){ s += __shfl_xor(s, o, 64); sq += __shfl_xor(sq, o, 64); }
  float mean = s*(1.f/DM);
  float var  = sq*(1.f/DM) - mean*mean;
  float rstd = rsqrtf(var + 1e-5f);
  #pragma unroll
  for (int i = 0; i < 12; i++){
    int c = lane + 64*i;
    float o = (v[i]-mean)*rstd*w[c] + bi[c];
    if (fout) fout[(size_t)row*DM + c] = o;
    if (bout) bout[(size_t)row*DM + c] = f2b(o);
  }
}

__global__ __launch_bounds__(256) void k_lnfin(const float* __restrict__ mlpo,
    const float* __restrict__ resd, const float* __restrict__ w, const float* __restrict__ bi,
    float* __restrict__ h, float* __restrict__ res){
  int wv = threadIdx.x >> 6, lane = threadIdx.x & 63;
  int row = blockIdx.x*4 + wv;
  if (row >= ML) return;
  const float* x0 = mlpo + (size_t)row*DM;
  const float* x1 = mlpo + (size_t)(ML + row)*DM;
  float v0[12], v1[12]; float s0=0,q0=0,s1=0,q1=0;
  #pragma unroll
  for (int i = 0; i < 12; i++){
    int c = lane + 64*i;
    float a = x0[c], b = x1[c];
    v0[i]=a; v1[i]=b; s0+=a; q0+=a*a; s1+=b; q1+=b*b;
  }
  #pragma unroll
  for (int o = 32; o; o >>= 1){
    s0 += __shfl_xor(s0, o, 64); q0 += __shfl_xor(q0, o, 64);
    s1 += __shfl_xor(s1, o, 64); q1 += __shfl_xor(q1, o, 64);
  }
  float m0 = s0*(1.f/DM), m1 = s1*(1.f/DM);
  float r0 = rsqrtf(q0*(1.f/DM) - m0*m0 + 1e-5f);
  float r1 = rsqrtf(q1*(1.f/DM) - m1*m1 + 1e-5f);
  #pragma unroll
  for (int i = 0; i < 12; i++){
    int c = lane + 64*i;
    float o = ((v0[i]-m0)*r0 + (v1[i]-m1)*r1)*w[c] + 2.f*bi[c];
    h[(size_t)row*DM + c] = o;
    res[(size_t)row*DM + c] = resd[(size_t)row*DM + c] + resd[(size_t)(ML+row)*DM + c];
  }
}

// Bijective XCD-chunk remap (m204), m-major decompose (kept: halved FETCH_SIZE).
static __device__ __forceinline__ void tile_mn(int &mT, int &nT){
  int nx = gridDim.x;
  int orig = blockIdx.y * nx + blockIdx.x;
  int nwg = nx * gridDim.y;
  int q = nwg >> 3, r = nwg & 7;
  int xcd = orig & 7, j = orig >> 3;
  int wg = (xcd < r ? xcd*(q+1) : r*(q+1) + (xcd-r)*q) + j;
  mT = wg / nx; nT = wg - mT*nx;
}

// ---- MFMA GEMM core: 128(M) x TN(N) tile, BK=32, dbuf + counted vmcnt ----
// All LDS strides in SHORTS. A stage buffer = 4096 shorts; B = TN*32 shorts.
template<int TN>
static __device__ __forceinline__ void mgemm_core(
    const unsigned short* __restrict__ A, const unsigned short* __restrict__ W, int K,
    int m0, int n0,
    unsigned short* As, unsigned short* Bs, f32x4 (&acc)[4][TN/32]){
  const int NB = TN/32;            // B-frags per wave (4 or 2)
  const int NBS = TN/64;           // B stage instrs per thread (2 or 1)
  const int ABUF = 4096;           // shorts per A stage buffer
  const int BBUFS = TN*32;         // shorts per B stage buffer
  int t = threadIdx.x;
  int lane = t & 63, w = t >> 6;
  int wm = w & 1, wn = w >> 1;

  const unsigned short* gA[2]; unsigned short* lA[2];
  #pragma unroll
  for (int si = 0; si < 2; si++){
    int s = t + si*256;
    int row = ((s>>6)<<4) + (s & 15);
    int ko  = ((s>>4) & 3) << 3;
    gA[si] = A + (size_t)(m0+row)*K + ko;
    lA[si] = As + (size_t)s*8;
  }
  const unsigned short* gB[2]; unsigned short* lB[2];
  #pragma unroll
  for (int si = 0; si < NBS; si++){
    int s = t + si*256;
    int row = ((s>>6)<<4) + (s & 15);
    int ko  = ((s>>4) & 3) << 3;
    gB[si] = W + (size_t)(n0+row)*K + ko;
    lB[si] = Bs + (size_t)s*8;
  }

  // prologue: stage step 0 into buf 0
  #pragma unroll
  for (int si = 0; si < 2; si++)
    __builtin_amdgcn_global_load_lds((gas_t)gA[si], (las_t)lA[si], 16, 0, 0);
  #pragma unroll
  for (int si = 0; si < NBS; si++)
    __builtin_amdgcn_global_load_lds((gas_t)gB[si], (las_t)lB[si], 16, 0, 0);

  int NI = K >> 5;
  int cur = 0;
  for (int it = 0; it < NI; ++it){
    if (it + 1 < NI){
      int kn = (it+1) << 5, nb = cur ^ 1;
      #pragma unroll
      for (int si = 0; si < 2; si++)
        __builtin_amdgcn_global_load_lds((gas_t)(gA[si] + kn), (las_t)(lA[si] + nb*ABUF), 16, 0, 0);
      #pragma unroll
      for (int si = 0; si < NBS; si++)
        __builtin_amdgcn_global_load_lds((gas_t)(gB[si] + kn), (las_t)(lB[si] + nb*BBUFS), 16, 0, 0);
      if (TN == 128) asm volatile("s_waitcnt vmcnt(4)" ::: "memory");
      else           asm volatile("s_waitcnt vmcnt(3)" ::: "memory");
    } else {
      asm volatile("s_waitcnt vmcnt(0)" ::: "memory");
    }
    __builtin_amdgcn_s_barrier();
    __builtin_amdgcn_sched_barrier(0);
    const unsigned short* Ab = As + cur*ABUF;
    const unsigned short* Bb = Bs + cur*BBUFS;
    s16x8 af[4], bf[NB];
    #pragma unroll
    for (int i = 0; i < 4; i++) af[i] = *(const s16x8*)&Ab[((wm*4+i)*64 + lane)*8];
    #pragma unroll
    for (int j = 0; j < NB; j++) bf[j] = *(const s16x8*)&Bb[((wn*NB+j)*64 + lane)*8];
    #pragma unroll
    for (int i = 0; i < 4; i++)
      #pragma unroll
      for (int j = 0; j < NB; j++)
        acc[i][j] = __builtin_amdgcn_mfma_f32_16x16x32_bf16(af[i], bf[j], acc[i][j], 0, 0, 0);
    __builtin_amdgcn_s_barrier();
    __builtin_amdgcn_sched_barrier(0);
    cur ^= 1;
  }
}

__global__ __launch_bounds__(256) void k_mg0(const unsigned short* __restrict__ A,
    const unsigned short* __restrict__ W, const float* __restrict__ addsrc,
    float* __restrict__ Cf, int N, int K){
  __shared__ __align__(16) unsigned short As[8192], Bs[4096];
  int mT, nT; tile_mn(mT, nT);
  int m0 = mT*128, n0 = nT*64;
  f32x4 acc[4][2] = {};
  mgemm_core<64>(A, W, K, m0, n0, As, Bs, acc);
  int t = threadIdx.x, lane = t & 63, w = t >> 6;
  int wm = w & 1, wn = w >> 1;
  int cl = lane & 15, qd = lane >> 4;
  #pragma unroll
  for (int i = 0; i < 4; i++){
    int mbase = m0 + (wm*4+i)*16 + qd*4;
    #pragma unroll
    for (int j = 0; j < 2; j++){
      int n = n0 + (wn*2+j)*16 + cl;
      #pragma unroll
      for (int r = 0; r < 4; r++){
        int m = mbase + r;
        float v = acc[i][j][r];
        if (addsrc) v += addsrc[(size_t)(m & (ML-1))*N + n];
        Cf[(size_t)m*N + n] = v;
      }
    }
  }
}

__global__ __launch_bounds__(256) void k_mg1(const unsigned short* __restrict__ A,
    const unsigned short* __restrict__ W, const float* __restrict__ dtb,
    unsigned short* __restrict__ dlb, float* __restrict__ bcout, int K){
  __shared__ __align__(16) unsigned short As[8192], Bs[8192];
  int mT, nT; tile_mn(mT, nT);
  int m0 = mT*128, n0 = nT*128;
  f32x4 acc[4][4] = {};
  mgemm_core<128>(A, W, K, m0, n0, As, Bs, acc);
  int t = threadIdx.x, lane = t & 63, w = t >> 6;
  int wm = w & 1, wn = w >> 1;
  int cl = lane & 15, qd = lane >> 4;
  #pragma unroll
  for (int i = 0; i < 4; i++){
    int mbase = m0 + (wm*4+i)*16 + qd*4;
    #pragma unroll
    for (int j = 0; j < 4; j++){
      int n = n0 + (wn*4+j)*16 + cl;
      #pragma unroll
      for (int r = 0; r < 4; r++){
        int m = mbase + r;
        float v = acc[i][j][r];
        if (n < DI) dlb[(size_t)m*DI + n] = f2b(softplus_(v + dtb[n]));
        else if (n < DI + 32) bcout[(size_t)m*32 + (n - DI)] = v;
      }
    }
  }
}

__global__ __launch_bounds__(256) void k_mg2(const unsigned short* __restrict__ A,
    const unsigned short* __restrict__ W, unsigned short* __restrict__ Cb, int N, int K){
  __shared__ __align__(16) unsigned short As[8192], Bs[8192];
  int mT, nT; tile_mn(mT, nT);
  int m0 = mT*128, n0 = nT*128;
  f32x4 acc[4][4] = {};
  mgemm_core<128>(A, W, K, m0, n0, As, Bs, acc);
  int t = threadIdx.x, lane = t & 63, w = t >> 6;
  int wm = w & 1, wn = w >> 1;
  int cl = lane & 15, qd = lane >> 4;
  #pragma unroll
  for (int i = 0; i < 4; i++){
    int mbase = m0 + (wm*4+i)*16 + qd*4;
    #pragma unroll
    for (int j = 0; j < 4; j++){
      int n = n0 + (wn*4+j)*16 + cl;
      #pragma unroll
      for (int r = 0; r < 4; r++){
        int m = mbase + r;
        Cb[(size_t)m*N + n] = f2b(acc[i][j][r]);
      }
    }
  }
}

__global__ void k_conv(const unsigned short* __restrict__ xzb, const float* __restrict__ w,
                       const float* __restrict__ bi, unsigned short* __restrict__ xcb){
  int idx = blockIdx.x*256 + threadIdx.x;   // over 2*ML*DI
  if (idx >= 2*ML*DI) return;
  int d = idx % DI; int r = idx / DI;
  int bl = r % ML; int dir = r / ML;
  int t = bl % LL; int b = bl / LL;
  float acc = bi[d];
  #pragma unroll
  for (int k = 0; k < 4; k++){
    int tp = dir ? (t + 3 - k) : (t - 3 + k);
    if (tp >= 0 && tp < LL)
      acc += w[d*4 + k] * b2f(xzb[((size_t)(b*LL + tp))*(2*DI) + d]);
  }
  xcb[idx] = f2b(silu_(acc));
}

__global__ __launch_bounds__(256) void k_scan1(
    const unsigned short* __restrict__ dlb, const unsigned short* __restrict__ xcb,
    const float* __restrict__ bc, const float* __restrict__ A_log,
    float* __restrict__ sA, float* __restrict__ sH){
  __shared__ float Bsh[CLEN*16];
  int blk = blockIdx.x;
  int dgrp = blk % (DI/256); int rest = blk / (DI/256);
  int ch = rest % NCH; rest /= NCH;
  int b = rest & 1; int dir = rest >> 1;
  int d = dgrp*256 + threadIdx.x;
  int t0 = dir ? (LL-1 - ch*CLEN) : ch*CLEN;
  long step = dir ? -1 : 1;
  long row0 = (long)dir*ML + b*LL + t0;
  #pragma unroll
  for (int rep = 0; rep < CLEN*16/256; rep++){
    int e = threadIdx.x + rep*256;
    int s = e >> 4, n = e & 15;
    Bsh[e] = bc[(size_t)(row0 + s*step)*32 + n];
  }
  __syncthreads();
  float ea[16];
  #pragma unroll
  for (int n = 0; n < 16; n++) ea[n] = -__expf(A_log[d*16 + n]) * 1.44269504f;
  float h[16], P[16];
  #pragma unroll
  for (int n = 0; n < 16; n++){ h[n] = 0.f; P[n] = 1.f; }
  long row = row0;
  for (int s = 0; s < CLEN; s++){
    float de = b2f(dlb[(size_t)row*DI + d]);
    float u  = b2f(xcb[(size_t)row*DI + d]);
    float duu = de*u;
    float Ba[16];
    const f32x4* Bv = (const f32x4*)&Bsh[s*16];
    *(f32x4*)&Ba[0] = Bv[0]; *(f32x4*)&Ba[4] = Bv[1];
    *(f32x4*)&Ba[8] = Bv[2]; *(f32x4*)&Ba[12] = Bv[3];
    #pragma unroll
    for (int n = 0; n < 16; n++){
      float dA = exp2f(de*ea[n]);
      h[n] = dA*h[n] + duu*Ba[n];
      P[n] *= dA;
    }
    row += step;
  }
  size_t sbase = ((((size_t)dir*BB + b)*NCH + ch)*DI + d)*16;
  #pragma unroll
  for (int n = 0; n < 16; n++){ sA[sbase+n] = P[n]; sH[sbase+n] = h[n]; }
}

__global__ __launch_bounds__(256) void k_prefix(
    float* __restrict__ sA, const float* __restrict__ sH){
  int gid = blockIdx.x*256 + threadIdx.x;  // over 2*BB*DI*16
  int dn = gid % (DI*16);
  int db_ = gid / (DI*16);
  float h = 0.f;
  size_t base = (size_t)db_*NCH*DI*16 + dn;
  for (int ch = 0; ch < NCH; ch++){
    size_t idx = base + (size_t)ch*DI*16;
    float a = sA[idx], hh = sH[idx];
    sA[idx] = h;
    h = hh + a*h;
  }
}

__global__ __launch_bounds__(256) void k_scan2(
    const unsigned short* __restrict__ dlb, const unsigned short* __restrict__ xcb,
    const float* __restrict__ bc, const unsigned short* __restrict__ xzb,
    const float* __restrict__ A_log, const float* __restrict__ Dp,
    const float* __restrict__ h0, unsigned short* __restrict__ y){
  __shared__ float BCs[CLEN*32];
  int blk = blockIdx.x;
  int dgrp = blk % (DI/256); int rest = blk / (DI/256);
  int ch = rest % NCH; rest /= NCH;
  int b = rest & 1; int dir = rest >> 1;
  int d = dgrp*256 + threadIdx.x;
  int t0 = dir ? (LL-1 - ch*CLEN) : ch*CLEN;
  long step = dir ? -1 : 1;
  long row0 = (long)dir*ML + b*LL + t0;
  #pragma unroll
  for (int rep = 0; rep < CLEN*32/256; rep++){
    int e = threadIdx.x + rep*256;
    int s = e >> 5, n = e & 31;
    BCs[e] = bc[(size_t)(row0 + s*step)*32 + n];
  }
  __syncthreads();
  float ea[16];
  #pragma unroll
  for (int n = 0; n < 16; n++) ea[n] = -__expf(A_log[d*16 + n]) * 1.44269504f;
  float dD = Dp[d];
  float h[16];
  size_t hbase = ((((size_t)dir*BB + b)*NCH + ch)*DI + d)*16;
  #pragma unroll
  for (int n = 0; n < 16; n++) h[n] = h0[hbase + n];
  long row = row0;
  long zoff = (long)dir*ML;
  for (int s = 0; s < CLEN; s++){
    float de = b2f(dlb[(size_t)row*DI + d]);
    float u  = b2f(xcb[(size_t)row*DI + d]);
    float z  = b2f(xzb[(size_t)(row - zoff)*(2*DI) + DI + d]);
    float duu = de*u;
    float Ba[16], Ca[16];
    const f32x4* Bv = (const f32x4*)&BCs[s*32];
    *(f32x4*)&Ba[0] = Bv[0]; *(f32x4*)&Ba[4] = Bv[1];
    *(f32x4*)&Ba[8] = Bv[2]; *(f32x4*)&Ba[12] = Bv[3];
    *(f32x4*)&Ca[0] = Bv[4]; *(f32x4*)&Ca[4] = Bv[5];
    *(f32x4*)&Ca[8] = Bv[6]; *(f32x4*)&Ca[12] = Bv[7];
    float p0 = 0.f, p1 = 0.f, p2 = 0.f, p3 = 0.f;
    #pragma unroll
    for (int n = 0; n < 16; n += 4){
      float dA0 = exp2f(de*ea[n]),   dA1 = exp2f(de*ea[n+1]);
      float dA2 = exp2f(de*ea[n+2]), dA3 = exp2f(de*ea[n+3]);
      h[n]   = dA0*h[n]   + duu*Ba[n];
      h[n+1] = dA1*h[n+1] + duu*Ba[n+1];
      h[n+2] = dA2*h[n+2] + duu*Ba[n+2];
      h[n+3] = dA3*h[n+3] + duu*Ba[n+3];
      p0 = fmaf(h[n],   Ca[n],   p0);
      p1 = fmaf(h[n+1], Ca[n+1], p1);
      p2 = fmaf(h[n+2], Ca[n+2], p2);
      p3 = fmaf(h[n+3], Ca[n+3], p3);
    }
    float p = (p0+p1) + (p2+p3);
    y[(size_t)row*DI + d] = f2b((p + u*dD) * silu_(z));
    row += step;
  }
}

__global__ void k_gate(const unsigned short* __restrict__ fc1o, unsigned short* __restrict__ g){
  int idx = blockIdx.x*256 + threadIdx.x;   // over 2*ML*DINT
  if (idx >= 2*ML*DINT) return;
  int i = idx % DINT; int bl = idx / DINT;
  float aa = b2f(fc1o[(size_t)bl*2*DINT + i]);
  float gt = b2f(fc1o[(size_t)bl*2*DINT + DINT + i]);
  g[idx] = f2b(aa * silu_(gt));
}

__global__ __launch_bounds__(256) void k_mean(const float* __restrict__ x, float* __restrict__ out){
  __shared__ float red[4][64];
  int dd = threadIdx.x & 63, part = threadIdx.x >> 6;
  int d = blockIdx.x*64 + dd;
  int b = blockIdx.y;
  float s = 0.f;
  int tb = part*256;
  for (int t = tb; t < tb + 256; t++) s += x[((size_t)(b*LL + t))*DM + d];
  red[part][dd] = s;
  __syncthreads();
  if (part == 0)
    out[b*DM + d] = (red[0][dd]+red[1][dd]+red[2][dd]+red[3][dd])*(1.f/LL);
}

extern "C" void kernel_launch(void* const* d_in, const int* in_sizes, int n_in,
                              void* d_out, int out_size, void* d_ws, size_t ws_size,
                              hipStream_t stream){
  const int*   ids     = (const int*)d_in[0];
  const float* embed   = (const float*)d_in[1];
  const float* norm_w  = (const float*)d_in[2];
  const float* norm_b  = (const float*)d_in[3];
  const float* in_proj = (const float*)d_in[4];
  const float* conv_w  = (const float*)d_in[5];
  const float* conv_b  = (const float*)d_in[6];
  const float* x_proj  = (const float*)d_in[7];
  const float* dt_w    = (const float*)d_in[8];
  const float* dt_b    = (const float*)d_in[9];
  const float* A_log   = (const float*)d_in[10];
  const float* Dp      = (const float*)d_in[11];
  const float* out_pj  = (const float*)d_in[12];
  const float* norm2_w = (const float*)d_in[13];
  const float* norm2_b = (const float*)d_in[14];
  const float* fc1     = (const float*)d_in[15];
  const float* fc2     = (const float*)d_in[16];
  const float* normf_w = (const float*)d_in[17];
  const float* normf_b = (const float*)d_in[18];
  float* out = (float*)d_out;

  const size_t BLD   = (size_t)ML*DM;
  const size_t BLDI  = (size_t)ML*DI;
  const size_t SUMN  = (size_t)2*BB*NCH*DI*16;

  float* f = (float*)d_ws; size_t off = 0;
  float* h     = f+off; off += BLD;
  float* res   = f+off; off += BLD;
  float* rc    = f+off; off += BLD;
  float* resd  = f+off; off += 2*BLD;
  float* bc    = f+off; off += (size_t)2*ML*32;
  float* sA    = f+off; off += SUMN;    // h0 overwrites in place
  float* sH    = f+off; off += SUMN;    // gb aliases after prefix
  unsigned short* gb = (unsigned short*)sH;
  unsigned short* u16 = (unsigned short*)(f + off); size_t uo = 0;
  unsigned short* xlnb = u16+uo; uo += BLD;
  unsigned short* x2b  = u16+uo; uo += 2*BLD;
  unsigned short* xzb  = u16+uo; uo += 2*BLDI;
  unsigned short* xcb  = u16+uo; uo += 2*BLDI;
  unsigned short* dlb  = u16+uo; uo += 2*BLDI;
  unsigned short* wts  = u16+uo;
  const size_t W_IP = (size_t)2*DI*DM, W_OP = (size_t)DM*DI, W_F1 = (size_t)2*DINT*DM,
               W_F2 = (size_t)DM*DINT, W_BG = (size_t)1664*DI;
  const size_t WLAY = W_IP + W_OP + W_F1 + W_F2 + W_BG;
  unsigned short* yb   = xcb;
  unsigned short* fc1o = xcb;            // spans xcb+dlb
  float*          mlpo = (float*)xcb;    // after fc1o dead
  (void)ws_size; (void)in_sizes; (void)n_in; (void)out_size;

  dim3 blk(256);
  auto cdiv = [](int a, int b){ return (a + b - 1)/b; };
  const int scan_blocks = 2*2*NCH*(DI/256);

  // weight prep (both layers, 3 launches, no activation deps)
  Seg8 sg; int cum = 0;
  for (int l = 0; l < 2; l++){
    unsigned short* wl = wts + (size_t)l*WLAY;
    sg.src[l*4+0] = in_proj + (size_t)l*W_IP; sg.dst[l*4+0] = wl;
    sg.src[l*4+1] = out_pj  + (size_t)l*W_OP; sg.dst[l*4+1] = wl + W_IP;
    sg.src[l*4+2] = fc1     + (size_t)l*W_F1; sg.dst[l*4+2] = wl + W_IP + W_OP;
    sg.src[l*4+3] = fc2     + (size_t)l*W_F2; sg.dst[l*4+3] = wl + W_IP + W_OP + W_F1;
  }
  { int sz[8] = {(int)W_IP,(int)W_OP,(int)W_F1,(int)W_F2,(int)W_IP,(int)W_OP,(int)W_F1,(int)W_F2};
    sg.cum[0]=0; for (int i = 0; i < 8; i++){ cum += sz[i]; sg.cum[i+1] = cum; } }
  k_f2bseg<<<cdiv(cum,256), blk, 0, stream>>>(sg);
  for (int l = 0; l < 2; l++)
    k_wbig<<<cdiv(1664*DI,256), blk, 0, stream>>>(dt_w + (size_t)l*DI*DTR,
        x_proj + (size_t)l*(DTR+2*NST)*DI, wts + (size_t)l*WLAY + W_IP + W_OP + W_F1 + W_F2);

  k_embed<<<cdiv(ML*DM,256), blk, 0, stream>>>(ids, embed, h);

  for (int l = 0; l < NLAYER; l++){
    unsigned short* wl   = wts + (size_t)l*WLAY;
    unsigned short* wib  = wl;
    unsigned short* wob  = wl + W_IP;
    unsigned short* wf1b = wl + W_IP + W_OP;
    unsigned short* wf2b = wl + W_IP + W_OP + W_F1;
    unsigned short* wbig = wl + W_IP + W_OP + W_F1 + W_F2;
    const float* nw  = norm_w  + l*DM;
    const float* nb  = norm_b  + l*DM;
    const float* cw  = conv_w  + (size_t)l*DI*4;
    const float* cb  = conv_b  + (size_t)l*DI;
    const float* db  = dt_b    + (size_t)l*DI;
    const float* al  = A_log   + (size_t)l*DI*NST;
    const float* dpl = Dp      + (size_t)l*DI;
    const float* n2w = norm2_w + l*DM;
    const float* n2b = norm2_b + l*DM;

    k_ln<<<ML/4, blk, 0, stream>>>(h, (l==0)?nullptr:res, nw, nb, rc, nullptr, xlnb, ML);
    k_mg2<<<dim3(2*DI/128, ML/128), blk, 0, stream>>>(xlnb, wib, xzb, 2*DI, DM);
    k_conv<<<cdiv(2*ML*DI,256), blk, 0, stream>>>(xzb, cw, cb, xcb);
    k_mg1<<<dim3(1664/128, 2*ML/128), blk, 0, stream>>>(xcb, wbig, db, dlb, bc, DI);
    k_scan1<<<scan_blocks, blk, 0, stream>>>(dlb, xcb, bc, al, sA, sH);
    k_prefix<<<(2*BB*DI*16)/256, blk, 0, stream>>>(sA, sH);
    k_scan2<<<scan_blocks, blk, 0, stream>>>(dlb, xcb, bc, xzb, al, dpl, sA, yb);
    k_mg0<<<dim3(DM/64, 2*ML/128), blk, 0, stream>>>(yb, wob, rc, resd, DM, DI);
    k_ln<<<2*ML/4, blk, 0, stream>>>(resd, nullptr, n2w, n2b, nullptr, nullptr, x2b, 2*ML);
    k_mg2<<<dim3(2*DINT/128, 2*ML/128), blk, 0, stream>>>(x2b, wf1b, fc1o, 2*DINT, DM);
    k_gate<<<cdiv(2*ML*DINT,256), blk, 0, stream>>>(fc1o, gb);
    k_mg0<<<dim3(DM/64, 2*ML/128), blk, 0, stream>>>(gb, wf2b, nullptr, mlpo, DM, DINT);
    k_lnfin<<<ML/4, blk, 0, stream>>>(mlpo, resd, normf_w, normf_b, h, res);
  }

  k_ln<<<ML/4, blk, 0, stream>>>(h, res, normf_w, normf_b, nullptr, rc, nullptr, ML);
  k_mean<<<dim3(DM/64, BB), blk, 0, stream>>>(rc, out);
}